// Round 3
// baseline (145.542 us; speedup 1.0000x reference)
//
#include <hip/hip_runtime.h>

typedef __attribute__((ext_vector_type(4))) float f32x4;
typedef __attribute__((ext_vector_type(8))) __bf16 bf16x8;
typedef __attribute__((ext_vector_type(8))) unsigned short u16x8;
typedef __attribute__((ext_vector_type(4))) unsigned short u16x4;

// f32 -> bf16 round-to-nearest-even (bit pattern)
__device__ __forceinline__ unsigned short f2bf(float f) {
  unsigned u = __builtin_bit_cast(unsigned, f);
  u += 0x7fffu + ((u >> 16) & 1u);
  return (unsigned short)(u >> 16);
}

__device__ __forceinline__ f32x4 mfma16(bf16x8 a, bf16x8 b, f32x4 c) {
  return __builtin_amdgcn_mfma_f32_16x16x32_bf16(a, b, c, 0, 0, 0);
}

__device__ __forceinline__ void gload_lds16(const void* g, void* l) {
  __builtin_amdgcn_global_load_lds(
      (const __attribute__((address_space(1))) void*)g,
      (__attribute__((address_space(3))) void*)l, 16, 0, 0);
}

// sizes
#define NQK 6291456      // 2*12*4096*64  (one z-slice of qkv, elems)
#define NX 6291456       // 8192*768      (one X tensor, elems)
#define NW 589824        // 768*768

// ---------------------------------------------------------------------------
// Kernel 1: W [768K x 768N] f32  ->  Wt [768N x 768K] bf16   (x3 for q,k,v)
// ---------------------------------------------------------------------------
__global__ __launch_bounds__(256) void wtrans_kernel(
    const float* __restrict__ Wq, const float* __restrict__ Wk,
    const float* __restrict__ Wv, unsigned short* __restrict__ Wt) {
  __shared__ float tile[64][65];
  const int z = blockIdx.z;
  const float* __restrict__ src = (z == 0) ? Wq : (z == 1) ? Wk : Wv;
  unsigned short* __restrict__ dst = Wt + (size_t)z * NW;
  const int k0 = blockIdx.x * 64, n0 = blockIdx.y * 64;
  const int t = threadIdx.x;
  const int r = t >> 4, c4 = (t & 15) * 4;
#pragma unroll
  for (int p = 0; p < 4; ++p) {
    int rr = r + p * 16;
    f32x4 v = *(const f32x4*)(src + (size_t)(k0 + rr) * 768 + n0 + c4);
#pragma unroll
    for (int j = 0; j < 4; ++j) tile[rr][c4 + j] = v[j];
  }
  __syncthreads();
#pragma unroll
  for (int p = 0; p < 4; ++p) {
    int rn = r + p * 16;
    u16x4 o;
#pragma unroll
    for (int j = 0; j < 4; ++j) o[j] = f2bf(tile[c4 + j][rn]);
    *(u16x4*)(dst + (size_t)(n0 + rn) * 768 + k0 + c4) = o;
  }
}

// ---------------------------------------------------------------------------
// Kernel 2: X f32 -> bf16 (from_tensor, to_tensor)
// ---------------------------------------------------------------------------
__global__ __launch_bounds__(256) void xconv_kernel(
    const float* __restrict__ from_t, const float* __restrict__ to_t,
    unsigned short* __restrict__ xb) {
  const float* __restrict__ src = blockIdx.y ? to_t : from_t;
  unsigned short* __restrict__ dst = xb + (size_t)blockIdx.y * NX;
  const size_t i = ((size_t)blockIdx.x * 256 + threadIdx.x) * 8;
  f32x4 a = *(const f32x4*)(src + i);
  f32x4 b = *(const f32x4*)(src + i + 4);
  u16x8 o;
#pragma unroll
  for (int j = 0; j < 4; ++j) { o[j] = f2bf(a[j]); o[j + 4] = f2bf(b[j]); }
  *(u16x8*)(dst + i) = o;
}

// ---------------------------------------------------------------------------
// Kernel 3: QKV projection. C = Xb[8192x768] * W[768x768] + b  (bf16 MFMA)
// BK=64, A and B both via global_load_lds, (r&7)-XOR chunk swizzle.
// z=0 -> Q (scaled 0.125), z=1 -> K into qkvQK; z=2 -> V into Vtmp.
// ---------------------------------------------------------------------------
__global__ __launch_bounds__(256) void qkv_gemm_kernel(
    const unsigned short* __restrict__ Xb, const unsigned short* __restrict__ Wt,
    const float* __restrict__ bq, const float* __restrict__ bk,
    const float* __restrict__ bv, unsigned short* __restrict__ qkvQK,
    unsigned short* __restrict__ Vtmp) {
  __shared__ unsigned short A_lds[8192];  // [128m][64k] linear, src-swizzled
  __shared__ unsigned short B_lds[8192];  // [128n][64k]
  const int z = blockIdx.z;
  const unsigned short* __restrict__ X = Xb + (z ? (size_t)NX : 0);
  const unsigned short* __restrict__ Wz = Wt + (size_t)z * NW;
  const float* __restrict__ bias = (z == 0) ? bq : (z == 1) ? bk : bv;
  const int bm = blockIdx.x, bn = blockIdx.y;
  const int t = threadIdx.x, lane = t & 63, w = t >> 6;
  const int wm = (w >> 1) * 64, wn = (w & 1) * 64;
  const int l15 = lane & 15, cc = lane >> 4;

  f32x4 acc[4][4];
#pragma unroll
  for (int i = 0; i < 4; ++i)
#pragma unroll
    for (int j = 0; j < 4; ++j) acc[i][j] = (f32x4){0.f, 0.f, 0.f, 0.f};

  const unsigned short* Abase = X + (size_t)bm * 128 * 768;
  const unsigned short* Bbase = Wz + (size_t)bn * 128 * 768;

  for (int ks = 0; ks < 12; ++ks) {
#pragma unroll
    for (int p = 0; p < 4; ++p) {
      int wb = p * 4 + w;            // wave-chunk 0..15 (wave-uniform)
      int ch = wb * 64 + lane;       // 16B chunk 0..1023
      int r = ch >> 3, sl = ch & 7;
      int g = sl ^ (r & 7);
      gload_lds16(Abase + (size_t)r * 768 + ks * 64 + g * 8, &A_lds[wb * 512]);
      gload_lds16(Bbase + (size_t)r * 768 + ks * 64 + g * 8, &B_lds[wb * 512]);
    }
    __syncthreads();

    bf16x8 af[4][2], bfr[4][2];
#pragma unroll
    for (int mi = 0; mi < 4; ++mi) {
      int row = wm + mi * 16 + l15;
      const char* rp = (const char*)A_lds + row * 128;
#pragma unroll
      for (int kk = 0; kk < 2; ++kk)
        af[mi][kk] = *(const bf16x8*)(rp + (((cc + 4 * kk) ^ (row & 7)) << 4));
    }
#pragma unroll
    for (int ni = 0; ni < 4; ++ni) {
      int row = wn + ni * 16 + l15;
      const char* rp = (const char*)B_lds + row * 128;
#pragma unroll
      for (int kk = 0; kk < 2; ++kk)
        bfr[ni][kk] = *(const bf16x8*)(rp + (((cc + 4 * kk) ^ (row & 7)) << 4));
    }
#pragma unroll
    for (int kk = 0; kk < 2; ++kk)
#pragma unroll
      for (int mi = 0; mi < 4; ++mi)
#pragma unroll
        for (int ni = 0; ni < 4; ++ni)
          acc[mi][ni] = mfma16(af[mi][kk], bfr[ni][kk], acc[mi][ni]);
    __syncthreads();
  }

  const float qscale = (z == 0) ? 0.125f : 1.0f;
  unsigned short* __restrict__ dst =
      (z == 2) ? Vtmp : qkvQK + (size_t)z * NQK;
#pragma unroll
  for (int ni = 0; ni < 4; ++ni) {
    int gn = bn * 128 + wn + ni * 16 + l15;
    float bv_ = bias[gn];
    int hh = gn >> 6, dd = gn & 63;
#pragma unroll
    for (int mi = 0; mi < 4; ++mi) {
#pragma unroll
      for (int r = 0; r < 4; ++r) {
        int gm = bm * 128 + wm + mi * 16 + cc * 4 + r;
        int bb = gm >> 12, s = gm & 4095;
        float val = (acc[mi][ni][r] + bv_) * qscale;
        dst[((((size_t)bb * 12 + hh) * 4096 + s) * 64) + dd] = f2bf(val);
      }
    }
  }
}

// ---------------------------------------------------------------------------
// Kernel 4: V [b][h][4096s][64d] -> vT [b][h][64d][4096s]  (register 8x8)
// ---------------------------------------------------------------------------
__global__ __launch_bounds__(256) void vtrans_kernel(
    const unsigned short* __restrict__ Vtmp, unsigned short* __restrict__ vt) {
  const int bh = blockIdx.y;
  const int t = threadIdx.x;
  const int sg = t & 31, c = t >> 5;
  const int sbase = blockIdx.x * 256 + sg * 8;
  const unsigned short* __restrict__ src = Vtmp + (size_t)bh * 262144;
  u16x8 v[8];
#pragma unroll
  for (int i = 0; i < 8; ++i)
    v[i] = *(const u16x8*)(src + (size_t)(sbase + i) * 64 + c * 8);
#pragma unroll
  for (int j = 0; j < 8; ++j) {
    u16x8 o;
#pragma unroll
    for (int i = 0; i < 8; ++i) o[i] = v[i][j];
    *(u16x8*)(vt + ((size_t)bh * 64 + c * 8 + j) * 4096 + sbase) = o;
  }
}

// ---------------------------------------------------------------------------
// Kernel 5: block-sparse attention. K and V^T both staged via global_load_lds.
// ---------------------------------------------------------------------------
__global__ __launch_bounds__(256) void attn_kernel(
    const unsigned short* __restrict__ qkvQK, const unsigned short* __restrict__ vt,
    const int* __restrict__ to_mask, const int* __restrict__ rand_attn,
    float* __restrict__ out, float* __restrict__ part_o,
    float* __restrict__ part_ml) {
  __shared__ unsigned short K_lds[4096];    // [64key][64d], src-chunk swizzled
  __shared__ unsigned short VT_lds[4096];   // [64d][64key], src-chunk swizzled
  __shared__ unsigned short P_lds[4][1024]; // per-wave [16q][64k], swizzled
  __shared__ float penal[8][64];
  __shared__ int blist[8];

  const int bid = blockIdx.x;
  const int t = threadIdx.x, lane = t & 63, w = t >> 6;
  const int l15 = lane & 15, cc = lane >> 4;

  int b, h, m, nblk;
  bool full;
  if (bid < 1488) {
    full = false;
    m = bid % 62 + 1;
    int hb = bid / 62;
    h = hb % 12;
    b = hb / 12;
    nblk = (m == 1 || m == 62) ? 7 : 8;
    if (t == 0) {
      const int* rp = rand_attn + ((size_t)h * 62 + (m - 1)) * 3;
      if (m == 1) {
        blist[0] = 0; blist[1] = 1; blist[2] = 2; blist[3] = 63;
        blist[4] = rp[0]; blist[5] = rp[1]; blist[6] = rp[2];
      } else if (m == 62) {
        blist[0] = 0; blist[1] = 61; blist[2] = 62; blist[3] = 63;
        blist[4] = rp[0]; blist[5] = rp[1]; blist[6] = rp[2];
      } else {
        blist[0] = m - 1; blist[1] = m; blist[2] = m + 1;
        blist[3] = rp[0]; blist[4] = rp[1]; blist[5] = rp[2];
        blist[6] = 0; blist[7] = 63;
      }
    }
  } else {
    full = true;
    int cid = bid - 1488;
    int chunk = cid & 7;
    int rest = cid >> 3;
    m = (rest & 1) ? 63 : 0;
    h = (rest >> 1) % 12;
    b = rest / 24;
    nblk = 8;
    if (t < 8) blist[t] = chunk * 8 + t;
  }

  const unsigned short* qp = qkvQK + (((size_t)b * 12 + h) * 4096 + m * 64) * 64;
  const unsigned short* kp = qkvQK + NQK + (((size_t)b * 12 + h) * 4096) * 64;
  const unsigned short* vtp = vt + (((size_t)b * 12 + h) * 64) * 4096;

  bf16x8 aq[2];
  {
    int qrow = w * 16 + l15;
    aq[0] = *(const bf16x8*)(qp + qrow * 64 + cc * 8);
    aq[1] = *(const bf16x8*)(qp + qrow * 64 + 32 + cc * 8);
  }

  float m_run[4], l_run[4];
  f32x4 o_acc[4];
#pragma unroll
  for (int r = 0; r < 4; ++r) { m_run[r] = -INFINITY; l_run[r] = 0.f; }
#pragma unroll
  for (int dg = 0; dg < 4; ++dg) o_acc[dg] = (f32x4){0.f, 0.f, 0.f, 0.f};

  __syncthreads();  // blist visible

  // preload mask penalties for the whole block list
  {
    int ib = w;
#pragma unroll
    for (int pp = 0; pp < 2; ++pp, ib += 4)
      if (ib < nblk)
        penal[ib][lane] =
            (1.0f - (float)to_mask[(size_t)b * 4096 + blist[ib] * 64 + lane]) *
            (-1e9f);
  }

  for (int ib = 0; ib < nblk; ++ib) {
    const int kb = blist[ib];
    // stage K and V^T tiles via global_load_lds (source chunk permuted r&7)
#pragma unroll
    for (int p = 0; p < 2; ++p) {
      int wb = p * 4 + w;            // wave-chunk 0..7 (wave-uniform)
      int ch = wb * 64 + lane;
      int r = ch >> 3, sl = ch & 7;
      int g = sl ^ (r & 7);
      gload_lds16(kp + (size_t)(kb * 64 + r) * 64 + g * 8, &K_lds[wb * 512]);
      gload_lds16(vtp + (size_t)r * 4096 + kb * 64 + g * 8, &VT_lds[wb * 512]);
    }
    __syncthreads();

    // QK^T (scale already folded into Q)
    f32x4 sf[4];
#pragma unroll
    for (int kg = 0; kg < 4; ++kg) {
      int krow = kg * 16 + l15;
      const char* kb_ = (const char*)K_lds + krow * 128;
      int swz = (krow & 7) << 4;
      bf16x8 b0 = *(const bf16x8*)(kb_ + ((cc << 4) ^ swz));
      bf16x8 b1 = *(const bf16x8*)(kb_ + (((cc + 4) << 4) ^ swz));
      f32x4 zz = (f32x4){0.f, 0.f, 0.f, 0.f};
      zz = mfma16(aq[0], b0, zz);
      zz = mfma16(aq[1], b1, zz);
      sf[kg] = zz;
    }

    float sm[4][4];
#pragma unroll
    for (int kg = 0; kg < 4; ++kg) {
      float pen = penal[ib][kg * 16 + l15];
#pragma unroll
      for (int r = 0; r < 4; ++r) sm[kg][r] = sf[kg][r] + pen;
    }
    float mx[4];
#pragma unroll
    for (int r = 0; r < 4; ++r)
      mx[r] = fmaxf(fmaxf(sm[0][r], sm[1][r]), fmaxf(sm[2][r], sm[3][r]));
#pragma unroll
    for (int msk = 1; msk < 16; msk <<= 1)
#pragma unroll
      for (int r = 0; r < 4; ++r)
        mx[r] = fmaxf(mx[r], __shfl_xor(mx[r], msk, 64));

    // rescale only when some row's max grew (exact skip, fac==1 otherwise)
    bool need = false;
#pragma unroll
    for (int r = 0; r < 4; ++r) need = need || (mx[r] > m_run[r]);
    if (__any(need)) {
#pragma unroll
      for (int r = 0; r < 4; ++r) {
        float mn = fmaxf(m_run[r], mx[r]);
        float fac = __expf(m_run[r] - mn);
        m_run[r] = mn;
        l_run[r] *= fac;
#pragma unroll
        for (int dg = 0; dg < 4; ++dg) o_acc[dg][r] *= fac;
      }
    }

    float rs[4] = {0.f, 0.f, 0.f, 0.f};
    unsigned short pb[4][4];
#pragma unroll
    for (int kg = 0; kg < 4; ++kg)
#pragma unroll
      for (int r = 0; r < 4; ++r) {
        float p = __expf(sm[kg][r] - m_run[r]);
        rs[r] += p;
        pb[kg][r] = f2bf(p);
      }
#pragma unroll
    for (int msk = 1; msk < 16; msk <<= 1)
#pragma unroll
      for (int r = 0; r < 4; ++r) rs[r] += __shfl_xor(rs[r], msk, 64);
#pragma unroll
    for (int r = 0; r < 4; ++r) l_run[r] += rs[r];

    // P (C-layout) -> LDS (swizzled) -> A-frags, per-wave region
    char* pw = (char*)P_lds[w];
    const int kbase = l15 << 1;
#pragma unroll
    for (int r = 0; r < 4; ++r) {
      int q = cc * 4 + r;
      int rowoff = q * 128;
      int swz = (q & 7) << 4;
#pragma unroll
      for (int kg = 0; kg < 4; ++kg)
        *(unsigned short*)(pw + rowoff + ((kg * 32 + kbase) ^ swz)) = pb[kg][r];
    }
    bf16x8 ap[2];
    {
      int swz = (l15 & 7) << 4;
      const char* rp = pw + l15 * 128;
      ap[0] = *(const bf16x8*)(rp + ((cc << 4) ^ swz));
      ap[1] = *(const bf16x8*)(rp + (((cc + 4) << 4) ^ swz));
    }
    // PV
#pragma unroll
    for (int dg = 0; dg < 4; ++dg) {
      int d = dg * 16 + l15;
      const char* vb = (const char*)VT_lds + d * 128;
      int swz = (d & 7) << 4;
      bf16x8 b0 = *(const bf16x8*)(vb + ((cc << 4) ^ swz));
      bf16x8 b1 = *(const bf16x8*)(vb + (((cc + 4) << 4) ^ swz));
      o_acc[dg] = mfma16(ap[0], b0, o_acc[dg]);
      o_acc[dg] = mfma16(ap[1], b1, o_acc[dg]);
    }
    __syncthreads();
  }

  if (!full) {
#pragma unroll
    for (int r = 0; r < 4; ++r) {
      float inv = 1.0f / l_run[r];
      int s = m * 64 + w * 16 + cc * 4 + r;
#pragma unroll
      for (int dg = 0; dg < 4; ++dg) {
        int d = dg * 16 + l15;
        out[(((size_t)b * 4096 + s) * 12 + h) * 64 + d] = o_acc[dg][r] * inv;
      }
    }
  } else {
    const int chunk = (bid - 1488) & 7;
    const int row = (b * 12 + h) * 2 + (m ? 1 : 0);
    float* po = part_o + (((size_t)row * 8 + chunk) * 64) * 64;
    float* pml = part_ml + ((size_t)row * 8 + chunk) * 128;
#pragma unroll
    for (int r = 0; r < 4; ++r) {
      int q = w * 16 + cc * 4 + r;
#pragma unroll
      for (int dg = 0; dg < 4; ++dg) {
        int d = dg * 16 + l15;
        po[q * 64 + d] = o_acc[dg][r];
      }
      if (l15 == 0) {
        pml[q] = m_run[r];
        pml[64 + q] = l_run[r];
      }
    }
  }
}

// ---------------------------------------------------------------------------
// Kernel 6: merge 8 split-K partials per full row (48 rows).
// ---------------------------------------------------------------------------
__global__ __launch_bounds__(256) void combine_kernel(
    const float* __restrict__ part_o, const float* __restrict__ part_ml,
    float* __restrict__ out) {
  const int row = blockIdx.x;  // (b*12+h)*2 + (m==63)
  const int b = row / 24, h = (row >> 1) % 12, m = (row & 1) ? 63 : 0;
  const int t = threadIdx.x;
  const int q = t >> 2, d0 = (t & 3) * 16;

  float mc[8], lc[8];
  float M = -INFINITY;
#pragma unroll
  for (int c = 0; c < 8; ++c) {
    const float* pml = part_ml + ((size_t)row * 8 + c) * 128;
    mc[c] = pml[q];
    lc[c] = pml[64 + q];
    M = fmaxf(M, mc[c]);
  }
  float wgt[8], L = 0.f;
#pragma unroll
  for (int c = 0; c < 8; ++c) {
    wgt[c] = __expf(mc[c] - M);
    L += wgt[c] * lc[c];
  }
  f32x4 acc[4];
#pragma unroll
  for (int j = 0; j < 4; ++j) acc[j] = (f32x4){0.f, 0.f, 0.f, 0.f};
#pragma unroll
  for (int c = 0; c < 8; ++c) {
    const float* po = part_o + (((size_t)row * 8 + c) * 64 + q) * 64 + d0;
#pragma unroll
    for (int j = 0; j < 4; ++j) {
      f32x4 v = *(const f32x4*)(po + j * 4);
#pragma unroll
      for (int e = 0; e < 4; ++e) acc[j][e] += wgt[c] * v[e];
    }
  }
  const float inv = 1.0f / L;
  const int s = m * 64 + q;
  float* op = out + (((size_t)b * 4096 + s) * 12 + h) * 64 + d0;
#pragma unroll
  for (int j = 0; j < 4; ++j) {
    f32x4 v;
#pragma unroll
    for (int e = 0; e < 4; ++e) v[e] = acc[j][e] * inv;
    *(f32x4*)(op + j * 4) = v;
  }
}

// ---------------------------------------------------------------------------
extern "C" void kernel_launch(void* const* d_in, const int* in_sizes, int n_in,
                              void* d_out, int out_size, void* d_ws,
                              size_t ws_size, hipStream_t stream) {
  (void)in_sizes; (void)n_in; (void)out_size; (void)ws_size;
  const float* from_t = (const float*)d_in[0];
  const float* to_t = (const float*)d_in[1];
  const float* Wq = (const float*)d_in[2];
  const float* bq = (const float*)d_in[3];
  const float* Wk = (const float*)d_in[4];
  const float* bk = (const float*)d_in[5];
  const float* Wv = (const float*)d_in[6];
  const float* bv = (const float*)d_in[7];
  const int* to_mask = (const int*)d_in[8];
  const int* rand_attn = (const int*)d_in[9];
  float* out = (float*)d_out;

  // workspace layout (53.9 MB):
  //   Wt    : 3*768*768 bf16
  //   qkvQK : 2*2*12*4096*64 bf16 (Q scaled, K)
  //   Xb    : 2*8192*768 bf16   -- dead after gemm, then reused:
  //            vt (6.29M bf16) | part_o (1.57M f32) | part_ml (49K f32)
  // V natural layout (Vtmp) lives in d_out (fully overwritten later).
  unsigned short* Wt = (unsigned short*)d_ws;
  unsigned short* qkvQK = Wt + (size_t)3 * NW;
  unsigned short* Xb = qkvQK + (size_t)2 * NQK;
  unsigned short* Vtmp = (unsigned short*)d_out;
  unsigned short* vt = Xb;  // overlay, written after gemm
  float* part_o = (float*)(Xb + (size_t)NQK);
  float* part_ml = part_o + (size_t)48 * 8 * 64 * 64;

  wtrans_kernel<<<dim3(12, 12, 3), dim3(256), 0, stream>>>(Wq, Wk, Wv, Wt);
  xconv_kernel<<<dim3(3072, 2), dim3(256), 0, stream>>>(from_t, to_t, Xb);
  qkv_gemm_kernel<<<dim3(64, 6, 3), dim3(256), 0, stream>>>(
      Xb, Wt, bq, bk, bv, qkvQK, Vtmp);
  vtrans_kernel<<<dim3(16, 24), dim3(256), 0, stream>>>(Vtmp, vt);
  attn_kernel<<<dim3(1488 + 384), dim3(256), 0, stream>>>(
      qkvQK, vt, to_mask, rand_attn, out, part_o, part_ml);
  combine_kernel<<<dim3(48), dim3(256), 0, stream>>>(part_o, part_ml, out);
}

// Round 4
// 143.549 us; speedup vs baseline: 1.0139x; 1.0139x over previous
//
#include <hip/hip_runtime.h>

typedef __attribute__((ext_vector_type(4))) float f32x4;
typedef __attribute__((ext_vector_type(8))) __bf16 bf16x8;
typedef __attribute__((ext_vector_type(8))) unsigned short u16x8;
typedef __attribute__((ext_vector_type(4))) unsigned short u16x4;

// f32 -> bf16 round-to-nearest-even (bit pattern)
__device__ __forceinline__ unsigned short f2bf(float f) {
  unsigned u = __builtin_bit_cast(unsigned, f);
  u += 0x7fffu + ((u >> 16) & 1u);
  return (unsigned short)(u >> 16);
}

__device__ __forceinline__ f32x4 mfma16(bf16x8 a, bf16x8 b, f32x4 c) {
  return __builtin_amdgcn_mfma_f32_16x16x32_bf16(a, b, c, 0, 0, 0);
}

__device__ __forceinline__ void gload_lds16(const void* g, void* l) {
  __builtin_amdgcn_global_load_lds(
      (const __attribute__((address_space(1))) void*)g,
      (__attribute__((address_space(3))) void*)l, 16, 0, 0);
}

// sizes
#define NQK 6291456      // 2*12*4096*64  (one z-slice of qkv, elems)
#define NX 6291456       // 8192*768      (one X tensor, elems)
#define NW 589824        // 768*768

// ---------------------------------------------------------------------------
// Kernel 1: W [768K x 768N] f32  ->  Wt [768N x 768K] bf16   (x3 for q,k,v)
// ---------------------------------------------------------------------------
__global__ __launch_bounds__(256) void wtrans_kernel(
    const float* __restrict__ Wq, const float* __restrict__ Wk,
    const float* __restrict__ Wv, unsigned short* __restrict__ Wt) {
  __shared__ float tile[64][65];
  const int z = blockIdx.z;
  const float* __restrict__ src = (z == 0) ? Wq : (z == 1) ? Wk : Wv;
  unsigned short* __restrict__ dst = Wt + (size_t)z * NW;
  const int k0 = blockIdx.x * 64, n0 = blockIdx.y * 64;
  const int t = threadIdx.x;
  const int r = t >> 4, c4 = (t & 15) * 4;
#pragma unroll
  for (int p = 0; p < 4; ++p) {
    int rr = r + p * 16;
    f32x4 v = *(const f32x4*)(src + (size_t)(k0 + rr) * 768 + n0 + c4);
#pragma unroll
    for (int j = 0; j < 4; ++j) tile[rr][c4 + j] = v[j];
  }
  __syncthreads();
#pragma unroll
  for (int p = 0; p < 4; ++p) {
    int rn = r + p * 16;
    u16x4 o;
#pragma unroll
    for (int j = 0; j < 4; ++j) o[j] = f2bf(tile[c4 + j][rn]);
    *(u16x4*)(dst + (size_t)(n0 + rn) * 768 + k0 + c4) = o;
  }
}

// ---------------------------------------------------------------------------
// Kernel 2: X f32 -> bf16 (from_tensor, to_tensor)
// ---------------------------------------------------------------------------
__global__ __launch_bounds__(256) void xconv_kernel(
    const float* __restrict__ from_t, const float* __restrict__ to_t,
    unsigned short* __restrict__ xb) {
  const float* __restrict__ src = blockIdx.y ? to_t : from_t;
  unsigned short* __restrict__ dst = xb + (size_t)blockIdx.y * NX;
  const size_t i = ((size_t)blockIdx.x * 256 + threadIdx.x) * 8;
  f32x4 a = *(const f32x4*)(src + i);
  f32x4 b = *(const f32x4*)(src + i + 4);
  u16x8 o;
#pragma unroll
  for (int j = 0; j < 4; ++j) { o[j] = f2bf(a[j]); o[j + 4] = f2bf(b[j]); }
  *(u16x8*)(dst + i) = o;
}

// ---------------------------------------------------------------------------
// Kernel 3: QKV projection, double-buffered. C = Xb[8192x768]*W[768x768]+b.
// z=0 -> Q (scaled 0.125) natural; z=1 -> K natural; z=2 -> V^T [bh*64+d][s].
// 1-D grid with XCD swizzle (cpx = nblocks/8).
// ---------------------------------------------------------------------------
__global__ __launch_bounds__(256) void qkv_gemm_kernel(
    const unsigned short* __restrict__ Xb, const unsigned short* __restrict__ Wt,
    const float* __restrict__ bq, const float* __restrict__ bk,
    const float* __restrict__ bv, unsigned short* __restrict__ qkvQK,
    unsigned short* __restrict__ vt, int zoff, int cpx) {
  __shared__ unsigned short A_lds[2][8192];  // [128m][64k] linear, src-swizzled
  __shared__ unsigned short B_lds[2][8192];  // [128n][64k]
  const int bid0 = blockIdx.x;
  const int bid = (bid0 & 7) * cpx + (bid0 >> 3);  // XCD-contiguous chunks
  const int z = zoff + bid / 384;
  const int rem = bid % 384;
  const int bn = rem >> 6, bm = rem & 63;
  const unsigned short* __restrict__ X = Xb + (z ? (size_t)NX : 0);
  const unsigned short* __restrict__ Wz = Wt + (size_t)z * NW;
  const float* __restrict__ bias = (z == 0) ? bq : (z == 1) ? bk : bv;
  const int t = threadIdx.x, lane = t & 63, w = t >> 6;
  const int wm = (w >> 1) * 64, wn = (w & 1) * 64;
  const int l15 = lane & 15, cc = lane >> 4;

  f32x4 acc[4][4];
#pragma unroll
  for (int i = 0; i < 4; ++i)
#pragma unroll
    for (int j = 0; j < 4; ++j) acc[i][j] = (f32x4){0.f, 0.f, 0.f, 0.f};

  const unsigned short* Abase = X + (size_t)bm * 128 * 768;
  const unsigned short* Bbase = Wz + (size_t)bn * 128 * 768;

  auto STAGE = [&](int ks, int bufi) {
#pragma unroll
    for (int p = 0; p < 4; ++p) {
      int wb = p * 4 + w;            // wave-chunk 0..15 (wave-uniform)
      int ch = wb * 64 + lane;       // 16B chunk 0..1023
      int r = ch >> 3, sl = ch & 7;
      int g = sl ^ (r & 7);
      gload_lds16(Abase + (size_t)r * 768 + ks * 64 + g * 8,
                  &A_lds[bufi][wb * 512]);
      gload_lds16(Bbase + (size_t)r * 768 + ks * 64 + g * 8,
                  &B_lds[bufi][wb * 512]);
    }
  };

  STAGE(0, 0);
  __syncthreads();

  for (int ks = 0; ks < 12; ++ks) {
    const int cur = ks & 1;
    if (ks < 11) STAGE(ks + 1, cur ^ 1);

    bf16x8 af[4][2], bfr[4][2];
#pragma unroll
    for (int mi = 0; mi < 4; ++mi) {
      int row = wm + mi * 16 + l15;
      const char* rp = (const char*)A_lds[cur] + row * 128;
#pragma unroll
      for (int kk = 0; kk < 2; ++kk)
        af[mi][kk] = *(const bf16x8*)(rp + (((cc + 4 * kk) ^ (row & 7)) << 4));
    }
#pragma unroll
    for (int ni = 0; ni < 4; ++ni) {
      int row = wn + ni * 16 + l15;
      const char* rp = (const char*)B_lds[cur] + row * 128;
#pragma unroll
      for (int kk = 0; kk < 2; ++kk)
        bfr[ni][kk] = *(const bf16x8*)(rp + (((cc + 4 * kk) ^ (row & 7)) << 4));
    }
#pragma unroll
    for (int kk = 0; kk < 2; ++kk)
#pragma unroll
      for (int mi = 0; mi < 4; ++mi)
#pragma unroll
        for (int ni = 0; ni < 4; ++ni)
          acc[mi][ni] = mfma16(af[mi][kk], bfr[ni][kk], acc[mi][ni]);
    __syncthreads();  // next-tile loads landed + all waves done with [cur]
  }

  if (z < 2) {
    const float qscale = (z == 0) ? 0.125f : 1.0f;
    unsigned short* __restrict__ dst = qkvQK + (size_t)z * NQK;
#pragma unroll
    for (int ni = 0; ni < 4; ++ni) {
      int gn = bn * 128 + wn + ni * 16 + l15;
      float bv_ = bias[gn];
      int hh = gn >> 6, dd = gn & 63;
#pragma unroll
      for (int mi = 0; mi < 4; ++mi) {
#pragma unroll
        for (int r = 0; r < 4; ++r) {
          int gm = bm * 128 + wm + mi * 16 + cc * 4 + r;
          int bb = gm >> 12, s = gm & 4095;
          float val = (acc[mi][ni][r] + bv_) * qscale;
          dst[((((size_t)bb * 12 + hh) * 4096 + s) * 64) + dd] = f2bf(val);
        }
      }
    }
  } else {
    // V^T: vt[(bh*64+d)*4096 + s], r-index is s-contiguous -> packed stores
#pragma unroll
    for (int ni = 0; ni < 4; ++ni) {
      int gn = bn * 128 + wn + ni * 16 + l15;
      float bv_ = bias[gn];
      int hh = gn >> 6, dd = gn & 63;
#pragma unroll
      for (int mi = 0; mi < 4; ++mi) {
        int gm0 = bm * 128 + wm + mi * 16 + cc * 4;
        int bb = gm0 >> 12, s0 = gm0 & 4095;
        u16x4 o;
#pragma unroll
        for (int r = 0; r < 4; ++r) o[r] = f2bf(acc[mi][ni][r] + bv_);
        *(u16x4*)(vt + ((size_t)(bb * 12 + hh) * 64 + dd) * 4096 + s0) = o;
      }
    }
  }
}

// ---------------------------------------------------------------------------
// Kernel 4: block-sparse attention, double-buffered K/V^T staging.
// XCD swizzle with 78-block (b,h) groups: 62 sparse rows + 16 split-K chunks.
// ---------------------------------------------------------------------------
__global__ __launch_bounds__(256) void attn_kernel(
    const unsigned short* __restrict__ qkvQK, const unsigned short* __restrict__ vt,
    const int* __restrict__ to_mask, const int* __restrict__ rand_attn,
    float* __restrict__ out, float* __restrict__ part_o,
    float* __restrict__ part_ml) {
  __shared__ unsigned short K_lds[2][4096];   // [64key][64d], src-chunk swizzled
  __shared__ unsigned short VT_lds[2][4096];  // [64d][64key], src-chunk swizzled
  __shared__ unsigned short P_lds[4][1024];   // per-wave [16q][64k], swizzled
  __shared__ float penal[8][64];
  __shared__ int blist[8];

  const int bid0 = blockIdx.x;
  const int bid = (bid0 & 7) * 234 + (bid0 >> 3);  // 234 = 3 (b,h)-groups/XCD
  const int bh = bid / 78, r78 = bid % 78;
  const int h = bh % 12, b = bh / 12;
  const int t = threadIdx.x, lane = t & 63, w = t >> 6;
  const int l15 = lane & 15, cc = lane >> 4;

  int m, nblk, chunk = 0;
  bool full;
  if (r78 < 62) {
    full = false;
    m = r78 + 1;
    nblk = (m == 1 || m == 62) ? 7 : 8;
    if (t == 0) {
      const int* rp = rand_attn + ((size_t)h * 62 + (m - 1)) * 3;
      if (m == 1) {
        blist[0] = 0; blist[1] = 1; blist[2] = 2; blist[3] = 63;
        blist[4] = rp[0]; blist[5] = rp[1]; blist[6] = rp[2];
      } else if (m == 62) {
        blist[0] = 0; blist[1] = 61; blist[2] = 62; blist[3] = 63;
        blist[4] = rp[0]; blist[5] = rp[1]; blist[6] = rp[2];
      } else {
        blist[0] = m - 1; blist[1] = m; blist[2] = m + 1;
        blist[3] = rp[0]; blist[4] = rp[1]; blist[5] = rp[2];
        blist[6] = 0; blist[7] = 63;
      }
    }
  } else {
    full = true;
    int fr = r78 - 62;
    chunk = fr & 7;
    m = (fr >> 3) ? 63 : 0;
    nblk = 8;
    if (t < 8) blist[t] = chunk * 8 + t;
  }

  const unsigned short* qp = qkvQK + (((size_t)b * 12 + h) * 4096 + m * 64) * 64;
  const unsigned short* kp = qkvQK + NQK + (((size_t)b * 12 + h) * 4096) * 64;
  const unsigned short* vtp = vt + (((size_t)b * 12 + h) * 64) * 4096;

  bf16x8 aq[2];
  {
    int qrow = w * 16 + l15;
    aq[0] = *(const bf16x8*)(qp + qrow * 64 + cc * 8);
    aq[1] = *(const bf16x8*)(qp + qrow * 64 + 32 + cc * 8);
  }

  float m_run[4], l_run[4];
  f32x4 o_acc[4];
#pragma unroll
  for (int r = 0; r < 4; ++r) { m_run[r] = -INFINITY; l_run[r] = 0.f; }
#pragma unroll
  for (int dg = 0; dg < 4; ++dg) o_acc[dg] = (f32x4){0.f, 0.f, 0.f, 0.f};

  auto STAGE = [&](int kb, int bufi) {
#pragma unroll
    for (int p = 0; p < 2; ++p) {
      int wb = p * 4 + w;  // wave-chunk 0..7 (wave-uniform)
      int ch = wb * 64 + lane;
      int rr = ch >> 3, sl = ch & 7;
      int g = sl ^ (rr & 7);
      gload_lds16(kp + (size_t)(kb * 64 + rr) * 64 + g * 8,
                  &K_lds[bufi][wb * 512]);
      gload_lds16(vtp + (size_t)rr * 4096 + kb * 64 + g * 8,
                  &VT_lds[bufi][wb * 512]);
    }
  };

  __syncthreads();  // blist visible

  // prefetch mask penalties + first tile
  {
    int ib = w;
#pragma unroll
    for (int pp = 0; pp < 2; ++pp, ib += 4)
      if (ib < nblk)
        penal[ib][lane] =
            (1.0f - (float)to_mask[(size_t)b * 4096 + blist[ib] * 64 + lane]) *
            (-1e9f);
  }
  STAGE(blist[0], 0);
  __syncthreads();  // tile0 + penal visible

  for (int ib = 0; ib < nblk; ++ib) {
    const int cur = ib & 1;
    if (ib + 1 < nblk) STAGE(blist[ib + 1], cur ^ 1);

    // QK^T (scale already folded into Q)
    f32x4 sf[4];
    __builtin_amdgcn_s_setprio(1);
#pragma unroll
    for (int kg = 0; kg < 4; ++kg) {
      int krow = kg * 16 + l15;
      const char* kb_ = (const char*)K_lds[cur] + krow * 128;
      int swz = (krow & 7) << 4;
      bf16x8 b0 = *(const bf16x8*)(kb_ + ((cc << 4) ^ swz));
      bf16x8 b1 = *(const bf16x8*)(kb_ + (((cc + 4) << 4) ^ swz));
      f32x4 zz = (f32x4){0.f, 0.f, 0.f, 0.f};
      zz = mfma16(aq[0], b0, zz);
      zz = mfma16(aq[1], b1, zz);
      sf[kg] = zz;
    }
    __builtin_amdgcn_s_setprio(0);

    float sm[4][4];
#pragma unroll
    for (int kg = 0; kg < 4; ++kg) {
      float pen = penal[ib][kg * 16 + l15];
#pragma unroll
      for (int r = 0; r < 4; ++r) sm[kg][r] = sf[kg][r] + pen;
    }
    float mx[4];
#pragma unroll
    for (int r = 0; r < 4; ++r)
      mx[r] = fmaxf(fmaxf(sm[0][r], sm[1][r]), fmaxf(sm[2][r], sm[3][r]));
#pragma unroll
    for (int msk = 1; msk < 16; msk <<= 1)
#pragma unroll
      for (int r = 0; r < 4; ++r)
        mx[r] = fmaxf(mx[r], __shfl_xor(mx[r], msk, 64));

    // rescale only when some row's max grew (exact skip, fac==1 otherwise)
    bool need = false;
#pragma unroll
    for (int r = 0; r < 4; ++r) need = need || (mx[r] > m_run[r]);
    if (__any(need)) {
#pragma unroll
      for (int r = 0; r < 4; ++r) {
        float mn = fmaxf(m_run[r], mx[r]);
        float fac = __expf(m_run[r] - mn);
        m_run[r] = mn;
        l_run[r] *= fac;
#pragma unroll
        for (int dg = 0; dg < 4; ++dg) o_acc[dg][r] *= fac;
      }
    }

    float rs[4] = {0.f, 0.f, 0.f, 0.f};
    unsigned short pb[4][4];
#pragma unroll
    for (int kg = 0; kg < 4; ++kg)
#pragma unroll
      for (int r = 0; r < 4; ++r) {
        float p = __expf(sm[kg][r] - m_run[r]);
        rs[r] += p;
        pb[kg][r] = f2bf(p);
      }
#pragma unroll
    for (int msk = 1; msk < 16; msk <<= 1)
#pragma unroll
      for (int r = 0; r < 4; ++r) rs[r] += __shfl_xor(rs[r], msk, 64);
#pragma unroll
    for (int r = 0; r < 4; ++r) l_run[r] += rs[r];

    // P (C-layout) -> LDS (swizzled) -> A-frags, per-wave region
    char* pw = (char*)P_lds[w];
    const int kbase = l15 << 1;
#pragma unroll
    for (int r = 0; r < 4; ++r) {
      int q = cc * 4 + r;
      int rowoff = q * 128;
      int swz = (q & 7) << 4;
#pragma unroll
      for (int kg = 0; kg < 4; ++kg)
        *(unsigned short*)(pw + rowoff + ((kg * 32 + kbase) ^ swz)) = pb[kg][r];
    }
    bf16x8 ap[2];
    {
      int swz = (l15 & 7) << 4;
      const char* rp = pw + l15 * 128;
      ap[0] = *(const bf16x8*)(rp + ((cc << 4) ^ swz));
      ap[1] = *(const bf16x8*)(rp + (((cc + 4) << 4) ^ swz));
    }
    // PV
    __builtin_amdgcn_s_setprio(1);
#pragma unroll
    for (int dg = 0; dg < 4; ++dg) {
      int d = dg * 16 + l15;
      const char* vb = (const char*)VT_lds[cur] + d * 128;
      int swz = (d & 7) << 4;
      bf16x8 b0 = *(const bf16x8*)(vb + ((cc << 4) ^ swz));
      bf16x8 b1 = *(const bf16x8*)(vb + (((cc + 4) << 4) ^ swz));
      o_acc[dg] = mfma16(ap[0], b0, o_acc[dg]);
      o_acc[dg] = mfma16(ap[1], b1, o_acc[dg]);
    }
    __builtin_amdgcn_s_setprio(0);
    __syncthreads();  // next tile landed + all waves done with [cur]
  }

  if (!full) {
#pragma unroll
    for (int r = 0; r < 4; ++r) {
      float inv = 1.0f / l_run[r];
      int s = m * 64 + w * 16 + cc * 4 + r;
#pragma unroll
      for (int dg = 0; dg < 4; ++dg) {
        int d = dg * 16 + l15;
        out[(((size_t)b * 4096 + s) * 12 + h) * 64 + d] = o_acc[dg][r] * inv;
      }
    }
  } else {
    const int row = (b * 12 + h) * 2 + (m ? 1 : 0);
    float* po = part_o + (((size_t)row * 8 + chunk) * 64) * 64;
    float* pml = part_ml + ((size_t)row * 8 + chunk) * 128;
#pragma unroll
    for (int r = 0; r < 4; ++r) {
      int q = w * 16 + cc * 4 + r;
#pragma unroll
      for (int dg = 0; dg < 4; ++dg) {
        int d = dg * 16 + l15;
        po[q * 64 + d] = o_acc[dg][r];
      }
      if (l15 == 0) {
        pml[q] = m_run[r];
        pml[64 + q] = l_run[r];
      }
    }
  }
}

// ---------------------------------------------------------------------------
// Kernel 5: merge 8 split-K partials per full row (48 rows).
// ---------------------------------------------------------------------------
__global__ __launch_bounds__(256) void combine_kernel(
    const float* __restrict__ part_o, const float* __restrict__ part_ml,
    float* __restrict__ out) {
  const int row = blockIdx.x;  // (b*12+h)*2 + (m==63)
  const int b = row / 24, h = (row >> 1) % 12, m = (row & 1) ? 63 : 0;
  const int t = threadIdx.x;
  const int q = t >> 2, d0 = (t & 3) * 16;

  float mc[8], lc[8];
  float M = -INFINITY;
#pragma unroll
  for (int c = 0; c < 8; ++c) {
    const float* pml = part_ml + ((size_t)row * 8 + c) * 128;
    mc[c] = pml[q];
    lc[c] = pml[64 + q];
    M = fmaxf(M, mc[c]);
  }
  float wgt[8], L = 0.f;
#pragma unroll
  for (int c = 0; c < 8; ++c) {
    wgt[c] = __expf(mc[c] - M);
    L += wgt[c] * lc[c];
  }
  f32x4 acc[4];
#pragma unroll
  for (int j = 0; j < 4; ++j) acc[j] = (f32x4){0.f, 0.f, 0.f, 0.f};
#pragma unroll
  for (int c = 0; c < 8; ++c) {
    const float* po = part_o + (((size_t)row * 8 + c) * 64 + q) * 64 + d0;
#pragma unroll
    for (int j = 0; j < 4; ++j) {
      f32x4 v = *(const f32x4*)(po + j * 4);
#pragma unroll
      for (int e = 0; e < 4; ++e) acc[j][e] += wgt[c] * v[e];
    }
  }
  const float inv = 1.0f / L;
  const int s = m * 64 + q;
  float* op = out + (((size_t)b * 4096 + s) * 12 + h) * 64 + d0;
#pragma unroll
  for (int j = 0; j < 4; ++j) {
    f32x4 v;
#pragma unroll
    for (int e = 0; e < 4; ++e) v[e] = acc[j][e] * inv;
    *(f32x4*)(op + j * 4) = v;
  }
}

// ---------------------------------------------------------------------------
extern "C" void kernel_launch(void* const* d_in, const int* in_sizes, int n_in,
                              void* d_out, int out_size, void* d_ws,
                              size_t ws_size, hipStream_t stream) {
  (void)in_sizes; (void)n_in; (void)out_size; (void)ws_size;
  const float* from_t = (const float*)d_in[0];
  const float* to_t = (const float*)d_in[1];
  const float* Wq = (const float*)d_in[2];
  const float* bq = (const float*)d_in[3];
  const float* Wk = (const float*)d_in[4];
  const float* bk = (const float*)d_in[5];
  const float* Wv = (const float*)d_in[6];
  const float* bv = (const float*)d_in[7];
  const int* to_mask = (const int*)d_in[8];
  const int* rand_attn = (const int*)d_in[9];
  float* out = (float*)d_out;

  // workspace (53.9 MB):
  //   Wt    : 3*NW bf16
  //   qkvQK : 2*NQK bf16 (Q scaled, K)
  //   Xb    : 2*NX bf16.  After gemm_qk, Xb[0] (from_tensor) is dead ->
  //           gemm_v (reads Xb[1]) writes V^T there. After gemm_v, Xb[1] is
  //           dead -> attn split-K partials live there.
  unsigned short* Wt = (unsigned short*)d_ws;
  unsigned short* qkvQK = Wt + (size_t)3 * NW;
  unsigned short* Xb = qkvQK + (size_t)2 * NQK;
  unsigned short* vt = Xb;                              // overlay Xb[0]
  float* part_o = (float*)(Xb + (size_t)NX);            // overlay Xb[1]
  float* part_ml = part_o + (size_t)48 * 8 * 64 * 64;

  wtrans_kernel<<<dim3(12, 12, 3), dim3(256), 0, stream>>>(Wq, Wk, Wv, Wt);
  xconv_kernel<<<dim3(3072, 2), dim3(256), 0, stream>>>(from_t, to_t, Xb);
  qkv_gemm_kernel<<<dim3(768), dim3(256), 0, stream>>>(
      Xb, Wt, bq, bk, bv, qkvQK, vt, 0, 96);   // z=0,1 (Q,K)
  qkv_gemm_kernel<<<dim3(384), dim3(256), 0, stream>>>(
      Xb, Wt, bq, bk, bv, qkvQK, vt, 2, 48);   // z=2 (V^T)
  attn_kernel<<<dim3(1872), dim3(256), 0, stream>>>(
      qkvQK, vt, to_mask, rand_attn, out, part_o, part_ml);
  combine_kernel<<<dim3(48), dim3(256), 0, stream>>>(part_o, part_ml, out);
}